// Round 1
// baseline (537.806 us; speedup 1.0000x reference)
//
#include <hip/hip_runtime.h>

#define S_LEN 2048

typedef __attribute__((ext_vector_type(8))) short bf16x8;
typedef __attribute__((ext_vector_type(4))) float f32x4;
typedef unsigned long long u64;
typedef unsigned int u32;
typedef unsigned short u16;

#define MFMA16 __builtin_amdgcn_mfma_f32_16x16x32_bf16

// fp32 -> bf16 round-to-nearest-even
__device__ __forceinline__ u16 f2bf(float f) {
  union { float f; u32 u; } v; v.f = f;
  u32 r = v.u + 0x7fffu + ((v.u >> 16) & 1u);
  return (u16)(r >> 16);
}

// Load one 16B MFMA fragment (8 bf16) from an XOR-swizzled LDS tile.
// Tile: rows of `nblk` 16-byte blocks; block `blk` of row `row` stored at slot blk ^ (row & (nblk-1)).
__device__ __forceinline__ bf16x8 ldfrag(const u16* base, int row, int blk, int nblk) {
  const int xm = nblk - 1;
  const char* p = (const char*)base + (((row * nblk) + (blk ^ (row & xm))) << 4);
  return *(const bf16x8*)p;
}

// Stage a 128x64 fp32 tile (row stride 64) -> bf16 LDS tile, 8 blocks/row, xor (row&7).
__device__ __forceinline__ void stage_qk(u16* dst, const float* __restrict__ src, int t) {
#pragma unroll
  for (int i = 0; i < 8; ++i) {
    const int idx = t + (i << 8);
    const int row = idx >> 4, c4 = idx & 15;
    const float4 f = *(const float4*)(src + ((size_t)row << 6) + (c4 << 2));
    const u64 pk = (u64)f2bf(f.x) | ((u64)f2bf(f.y) << 16) |
                   ((u64)f2bf(f.z) << 32) | ((u64)f2bf(f.w) << 48);
    const int cb = c4 >> 1;
    char* p = (char*)dst + ((((row << 3) + (cb ^ (row & 7))) << 4) + ((c4 & 1) << 3));
    *(u64*)p = pk;
  }
}

// Stage a 128x64 fp32 V tile -> TRANSPOSED bf16 LDS (64 rows(d) x 128 cols(k)), 16 blocks/row, xor (row&15).
__device__ __forceinline__ void stage_v(u16* dst, const float* __restrict__ src, int t) {
#pragma unroll
  for (int i = 0; i < 4; ++i) {
    const int idx = t + (i << 8);
    const int kp = idx >> 4, c4 = idx & 15;
    const int kr = kp << 1;                       // even k row; handle kr, kr+1
    const float4 r0 = *(const float4*)(src + ((size_t)kr << 6) + (c4 << 2));
    const float4 r1 = *(const float4*)(src + ((size_t)(kr + 1) << 6) + (c4 << 2));
    const float a0[4] = {r0.x, r0.y, r0.z, r0.w};
    const float a1[4] = {r1.x, r1.y, r1.z, r1.w};
#pragma unroll
    for (int j = 0; j < 4; ++j) {
      const int d = (c4 << 2) + j;
      const u32 w = (u32)f2bf(a0[j]) | ((u32)f2bf(a1[j]) << 16);
      const int cb = kr >> 3;
      char* p = (char*)dst + ((((d << 4) + (cb ^ (d & 15))) << 4) + ((kr & 7) << 1));
      *(u32*)p = w;
    }
  }
}

// One block = one (b*h, 128-row q-tile). 256 threads = 4 waves.
// Phase 1: lse[q] = log(sum_k exp(q.k/8))  (fixed max 0 — scores are O(1), provably no overflow)
// Phase 2: W = mask ? s - lse : -1e9 (bf16), O^T = V^T * W^T, write out[b][q][h*64+d].
__global__ __launch_bounds__(256, 2) void attn_kernel(
    const float* __restrict__ gq, const float* __restrict__ gk,
    const float* __restrict__ gv, const int* __restrict__ gmask,
    float* __restrict__ gout) {
  __shared__ __align__(16) u16 sQ[128 * 64];
  __shared__ __align__(16) u16 sK[128 * 64];
  __shared__ __align__(16) u16 sV[64 * 128];   // transposed V; sRed aliases this (phase-1 tail only)
  __shared__ __align__(16) u16 sW[128 * 128];
  float* sRed = (float*)sV;                    // 4*128 floats, dead before first sV staging

  const int t = threadIdx.x;
  const int wv = t >> 6;
  const int lane = t & 63;
  const int c = lane & 15;
  const int quad = lane >> 4;

  const int bx = blockIdx.x;
  const int bh = bx & 63;
  const int qt = bx >> 6;
  const int q0 = qt << 7;

  const float* qg = gq + ((size_t)bh << 17) + ((size_t)q0 << 6);
  const float* kg = gk + ((size_t)bh << 17);
  const float* vg = gv + ((size_t)bh << 17);

  stage_qk(sQ, qg, t);

  float lacc[8];
#pragma unroll
  for (int i = 0; i < 8; ++i) lacc[i] = 0.f;

  // ---------------- phase 1: logsumexp ----------------
  for (int kt = 0; kt < 16; ++kt) {
    stage_qk(sK, kg + ((size_t)(kt << 7) << 6), t);
    __syncthreads();
#pragma unroll
    for (int tn = 0; tn < 8; ++tn) {
#pragma unroll
      for (int tr = 0; tr < 2; ++tr) {
        f32x4 acc = {0.f, 0.f, 0.f, 0.f};
#pragma unroll
        for (int ks = 0; ks < 2; ++ks) {
          bf16x8 a = ldfrag(sK, (wv << 5) + (tr << 4) + c, (ks << 2) + quad, 8);
          bf16x8 b = ldfrag(sQ, (tn << 4) + c, (ks << 2) + quad, 8);
          acc = MFMA16(a, b, acc, 0, 0, 0);
        }
        lacc[tn] += __expf(acc[0] * 0.125f) + __expf(acc[1] * 0.125f) +
                    __expf(acc[2] * 0.125f) + __expf(acc[3] * 0.125f);
      }
    }
    __syncthreads();
  }
  // reduce across quads (same (c,tn) within wave), then across waves via LDS
#pragma unroll
  for (int tn = 0; tn < 8; ++tn) {
    float v = lacc[tn];
    v += __shfl_xor(v, 16, 64);
    v += __shfl_xor(v, 32, 64);
    if (quad == 0) sRed[(wv << 7) + (tn << 4) + c] = v;
  }
  __syncthreads();
  float lq[8];  // lse for this lane's q columns: q = q0 + 16*tn + c
#pragma unroll
  for (int tn = 0; tn < 8; ++tn) {
    const int i = (tn << 4) + c;
    lq[tn] = __logf(sRed[i] + sRed[128 + i] + sRed[256 + i] + sRed[384 + i]);
  }
  __syncthreads();  // sRed (=sV) dead; phase 2 may overwrite

  // ---------------- phase 2: W = mask ? s-lse : -1e9 ; O^T = V^T W^T ----------------
  f32x4 oacc[4][2];
#pragma unroll
  for (int mt = 0; mt < 4; ++mt)
#pragma unroll
    for (int j = 0; j < 2; ++j) {
      f32x4 z = {0.f, 0.f, 0.f, 0.f};
      oacc[mt][j] = z;
    }

  for (int kt = 0; kt < 16; ++kt) {
    const int k0 = kt << 7;
    stage_qk(sK, kg + ((size_t)k0 << 6), t);
    stage_v(sV, vg + ((size_t)k0 << 6), t);
    __syncthreads();
    // QK^T (transposed orientation) + W formation
#pragma unroll
    for (int tn = 0; tn < 8; ++tn) {
#pragma unroll
      for (int tr = 0; tr < 2; ++tr) {
        f32x4 acc = {0.f, 0.f, 0.f, 0.f};
#pragma unroll
        for (int ks = 0; ks < 2; ++ks) {
          bf16x8 a = ldfrag(sK, (wv << 5) + (tr << 4) + c, (ks << 2) + quad, 8);
          bf16x8 b = ldfrag(sQ, (tn << 4) + c, (ks << 2) + quad, 8);
          acc = MFMA16(a, b, acc, 0, 0, 0);
        }
        // lane holds S^T[k = k0+32wv+16tr+4quad+j][q = q0+16tn+c]
        const int kc = (wv << 5) + (tr << 4) + (quad << 2);
        const int4 mm = *(const int4*)(gmask + (size_t)(q0 + (tn << 4) + c) * S_LEN + k0 + kc);
        const float l = lq[tn];
        const float w0 = mm.x ? acc[0] * 0.125f - l : -1e9f;
        const float w1 = mm.y ? acc[1] * 0.125f - l : -1e9f;
        const float w2 = mm.z ? acc[2] * 0.125f - l : -1e9f;
        const float w3 = mm.w ? acc[3] * 0.125f - l : -1e9f;
        const u64 pk = (u64)f2bf(w0) | ((u64)f2bf(w1) << 16) |
                       ((u64)f2bf(w2) << 32) | ((u64)f2bf(w3) << 48);
        const int row = (tn << 4) + c;      // q-local
        const int cb = kc >> 3;
        char* p = (char*)sW + ((((row << 4) + (cb ^ (row & 15))) << 4) + ((quad & 1) << 3));
        *(u64*)p = pk;
      }
    }
    __syncthreads();
    // PV: O^T[d][q] += V^T * W^T ; wave owns q-tiles {2wv, 2wv+1}, all 4 d-tiles
#pragma unroll
    for (int ks = 0; ks < 4; ++ks) {
      bf16x8 b0 = ldfrag(sW, ((wv << 1) << 4) + c, (ks << 2) + quad, 16);
      bf16x8 b1 = ldfrag(sW, (((wv << 1) + 1) << 4) + c, (ks << 2) + quad, 16);
#pragma unroll
      for (int mt = 0; mt < 4; ++mt) {
        bf16x8 a = ldfrag(sV, (mt << 4) + c, (ks << 2) + quad, 16);
        oacc[mt][0] = MFMA16(a, b0, oacc[mt][0], 0, 0, 0);
        oacc[mt][1] = MFMA16(a, b1, oacc[mt][1], 0, 0, 0);
      }
    }
    __syncthreads();
  }

  // epilogue: O^T C-layout: col(q) = c + 16*tn, row(d) = 16*mt + 4*quad + reg
  const int b = bh >> 4, h = bh & 15;
#pragma unroll
  for (int mt = 0; mt < 4; ++mt) {
#pragma unroll
    for (int tnn = 0; tnn < 2; ++tnn) {
      const int tn = (wv << 1) + tnn;
      float4 o;
      o.x = oacc[mt][tnn][0]; o.y = oacc[mt][tnn][1];
      o.z = oacc[mt][tnn][2]; o.w = oacc[mt][tnn][3];
      const size_t off = ((size_t)b * S_LEN + (size_t)(q0 + (tn << 4) + c)) * 1024
                       + (h << 6) + (mt << 4) + (quad << 2);
      *(float4*)(gout + off) = o;
    }
  }
}

extern "C" void kernel_launch(void* const* d_in, const int* in_sizes, int n_in,
                              void* d_out, int out_size, void* d_ws, size_t ws_size,
                              hipStream_t stream) {
  const float* q = (const float*)d_in[0];
  const float* k = (const float*)d_in[1];
  const float* v = (const float*)d_in[2];
  const int* mask = (const int*)d_in[3];
  (void)in_sizes; (void)n_in; (void)out_size; (void)d_ws; (void)ws_size;
  attn_kernel<<<dim3(1024), dim3(256), 0, stream>>>(q, k, v, mask, (float*)d_out);
}

// Round 2
// 523.270 us; speedup vs baseline: 1.0278x; 1.0278x over previous
//
#include <hip/hip_runtime.h>

#define S_LEN 2048

typedef __attribute__((ext_vector_type(8))) short bf16x8;
typedef __attribute__((ext_vector_type(4))) float f32x4;
typedef unsigned long long u64;
typedef unsigned int u32;
typedef unsigned short u16;

#define MFMA16 __builtin_amdgcn_mfma_f32_16x16x32_bf16

// fp32 -> bf16 round-to-nearest-even
__device__ __forceinline__ u16 f2bf(float f) {
  union { float f; u32 u; } v; v.f = f;
  u32 r = v.u + 0x7fffu + ((v.u >> 16) & 1u);
  return (u16)(r >> 16);
}

// Load one 16B MFMA fragment (8 bf16) from an XOR-swizzled LDS tile.
// Tile: rows of `nblk` 16-byte blocks; block `blk` of row `row` at slot blk ^ (row & (nblk-1)).
__device__ __forceinline__ bf16x8 ldfrag(const u16* base, int row, int blk, int nblk) {
  const int xm = nblk - 1;
  const char* p = (const char*)base + (((row * nblk) + (blk ^ (row & xm))) << 4);
  return *(const bf16x8*)p;
}

// Stage a 128x64 fp32 tile (row stride 64) -> bf16 LDS tile, 8 blocks/row, xor (row&7).
// scale folded into the conversion (use 0.125f for Q so scores need no post-scale).
__device__ __forceinline__ void stage_qk(u16* dst, const float* __restrict__ src, int t,
                                         float scale) {
#pragma unroll
  for (int i = 0; i < 8; ++i) {
    const int idx = t + (i << 8);
    const int row = idx >> 4, c4 = idx & 15;
    const float4 f = *(const float4*)(src + ((size_t)row << 6) + (c4 << 2));
    const u64 pk = (u64)f2bf(f.x * scale) | ((u64)f2bf(f.y * scale) << 16) |
                   ((u64)f2bf(f.z * scale) << 32) | ((u64)f2bf(f.w * scale) << 48);
    const int cb = c4 >> 1;
    char* p = (char*)dst + ((((row << 3) + (cb ^ (row & 7))) << 4) + ((c4 & 1) << 3));
    *(u64*)p = pk;
  }
}

// Stage a 128x64 fp32 V tile -> TRANSPOSED bf16 LDS (64 rows(d) x 128 cols(k)), 16 blocks/row.
__device__ __forceinline__ void stage_v(u16* dst, const float* __restrict__ src, int t) {
#pragma unroll
  for (int i = 0; i < 4; ++i) {
    const int idx = t + (i << 8);
    const int kp = idx >> 4, c4 = idx & 15;
    const int kr = kp << 1;
    const float4 r0 = *(const float4*)(src + ((size_t)kr << 6) + (c4 << 2));
    const float4 r1 = *(const float4*)(src + ((size_t)(kr + 1) << 6) + (c4 << 2));
    const float a0[4] = {r0.x, r0.y, r0.z, r0.w};
    const float a1[4] = {r1.x, r1.y, r1.z, r1.w};
#pragma unroll
    for (int j = 0; j < 4; ++j) {
      const int d = (c4 << 2) + j;
      const u32 w = (u32)f2bf(a0[j]) | ((u32)f2bf(a1[j]) << 16);
      const int cb = kr >> 3;
      char* p = (char*)dst + ((((d << 4) + (cb ^ (d & 15))) << 4) + ((kr & 7) << 1));
      *(u32*)p = w;
    }
  }
}

// One block = one (b*h, 128-row q-tile). 256 threads = 4 waves.
// Phase 1: lse[q] = log(sum_k exp(q.k/8))  (fixed max 0 — scores O(1), no overflow)
// Phase 2: W = mask ? s - lse : -1e9 (bf16), O^T = V^T * W^T, out[b][q][h*64+d].
// Q fragments are register-resident for the whole kernel (loaded once from sQ).
__global__ __launch_bounds__(256, 2) void attn_kernel(
    const float* __restrict__ gq, const float* __restrict__ gk,
    const float* __restrict__ gv, const int* __restrict__ gmask,
    float* __restrict__ gout) {
  __shared__ __align__(16) u16 sQ[128 * 64];
  __shared__ __align__(16) u16 sK[128 * 64];
  __shared__ __align__(16) u16 sV[64 * 128];   // sRed aliases (phase-1 tail only)
  __shared__ __align__(16) u16 sW[128 * 128];
  float* sRed = (float*)sV;

  const int t = threadIdx.x;
  const int wv = t >> 6;
  const int lane = t & 63;
  const int c = lane & 15;
  const int quad = lane >> 4;

  const int bx = blockIdx.x;
  const int bh = bx & 63;
  const int qt = bx >> 6;
  const int q0 = qt << 7;

  const float* qg = gq + ((size_t)bh << 17) + ((size_t)q0 << 6);
  const float* kg = gk + ((size_t)bh << 17);
  const float* vg = gv + ((size_t)bh << 17);

  stage_qk(sQ, qg, t, 0.125f);   // fold 1/sqrt(64) into Q (exact pow2 scale)
  __syncthreads();

  // Q fragments: register-resident for the whole kernel. qf[tn][ks].
  bf16x8 qf[8][2];
#pragma unroll
  for (int tn = 0; tn < 8; ++tn)
#pragma unroll
    for (int ks = 0; ks < 2; ++ks)
      qf[tn][ks] = ldfrag(sQ, (tn << 4) + c, (ks << 2) + quad, 8);

  float lacc[8];
#pragma unroll
  for (int i = 0; i < 8; ++i) lacc[i] = 0.f;

  // ---------------- phase 1: logsumexp ----------------
  for (int kt = 0; kt < 16; ++kt) {
    stage_qk(sK, kg + ((size_t)(kt << 7) << 6), t, 1.0f);
    __syncthreads();
    bf16x8 kf[2][2];
#pragma unroll
    for (int tr = 0; tr < 2; ++tr)
#pragma unroll
      for (int ks = 0; ks < 2; ++ks)
        kf[tr][ks] = ldfrag(sK, (wv << 5) + (tr << 4) + c, (ks << 2) + quad, 8);
#pragma unroll
    for (int tn = 0; tn < 8; ++tn) {
#pragma unroll
      for (int tr = 0; tr < 2; ++tr) {
        f32x4 acc = {0.f, 0.f, 0.f, 0.f};
#pragma unroll
        for (int ks = 0; ks < 2; ++ks)
          acc = MFMA16(kf[tr][ks], qf[tn][ks], acc, 0, 0, 0);
        lacc[tn] += __expf(acc[0]) + __expf(acc[1]) + __expf(acc[2]) + __expf(acc[3]);
      }
    }
    __syncthreads();
  }
  // reduce across quads (same (c,tn) within wave), then across waves via LDS
#pragma unroll
  for (int tn = 0; tn < 8; ++tn) {
    float v = lacc[tn];
    v += __shfl_xor(v, 16, 64);
    v += __shfl_xor(v, 32, 64);
    if (quad == 0) sRed[(wv << 7) + (tn << 4) + c] = v;
  }
  __syncthreads();
  float lq[8];
#pragma unroll
  for (int tn = 0; tn < 8; ++tn) {
    const int i = (tn << 4) + c;
    lq[tn] = __logf(sRed[i] + sRed[128 + i] + sRed[256 + i] + sRed[384 + i]);
  }
  __syncthreads();  // sRed (=sV) dead; phase 2 may overwrite

  // ---------------- phase 2: W = mask ? s-lse : -1e9 ; O^T = V^T W^T ----------------
  f32x4 oacc[4][2];
#pragma unroll
  for (int mt = 0; mt < 4; ++mt)
#pragma unroll
    for (int j = 0; j < 2; ++j) {
      f32x4 z = {0.f, 0.f, 0.f, 0.f};
      oacc[mt][j] = z;
    }

  for (int kt = 0; kt < 16; ++kt) {
    const int k0 = kt << 7;
    stage_qk(sK, kg + ((size_t)k0 << 6), t, 1.0f);
    stage_v(sV, vg + ((size_t)k0 << 6), t);
    __syncthreads();
    bf16x8 kf[2][2];
#pragma unroll
    for (int tr = 0; tr < 2; ++tr)
#pragma unroll
      for (int ks = 0; ks < 2; ++ks)
        kf[tr][ks] = ldfrag(sK, (wv << 5) + (tr << 4) + c, (ks << 2) + quad, 8);
    // QK^T (transposed orientation) + W formation
#pragma unroll
    for (int tn = 0; tn < 8; ++tn) {
#pragma unroll
      for (int tr = 0; tr < 2; ++tr) {
        f32x4 acc = {0.f, 0.f, 0.f, 0.f};
#pragma unroll
        for (int ks = 0; ks < 2; ++ks)
          acc = MFMA16(kf[tr][ks], qf[tn][ks], acc, 0, 0, 0);
        // lane holds S^T[k = k0+32wv+16tr+4quad+j][q = q0+16tn+c]
        const int kc = (wv << 5) + (tr << 4) + (quad << 2);
        const int4 mm = *(const int4*)(gmask + (size_t)(q0 + (tn << 4) + c) * S_LEN + k0 + kc);
        const float l = lq[tn];
        const float w0 = mm.x ? acc[0] - l : -1e9f;
        const float w1 = mm.y ? acc[1] - l : -1e9f;
        const float w2 = mm.z ? acc[2] - l : -1e9f;
        const float w3 = mm.w ? acc[3] - l : -1e9f;
        const u64 pk = (u64)f2bf(w0) | ((u64)f2bf(w1) << 16) |
                       ((u64)f2bf(w2) << 32) | ((u64)f2bf(w3) << 48);
        const int row = (tn << 4) + c;
        const int cb = kc >> 3;
        char* p = (char*)sW + ((((row << 4) + (cb ^ (row & 15))) << 4) + ((quad & 1) << 3));
        *(u64*)p = pk;
      }
    }
    __syncthreads();
    // PV: O^T[d][q] += V^T * W^T ; wave owns q-tiles {2wv, 2wv+1}, all 4 d-tiles
#pragma unroll
    for (int ks = 0; ks < 4; ++ks) {
      bf16x8 b0 = ldfrag(sW, ((wv << 1) << 4) + c, (ks << 2) + quad, 16);
      bf16x8 b1 = ldfrag(sW, (((wv << 1) + 1) << 4) + c, (ks << 2) + quad, 16);
#pragma unroll
      for (int mt = 0; mt < 4; ++mt) {
        bf16x8 a = ldfrag(sV, (mt << 4) + c, (ks << 2) + quad, 16);
        oacc[mt][0] = MFMA16(a, b0, oacc[mt][0], 0, 0, 0);
        oacc[mt][1] = MFMA16(a, b1, oacc[mt][1], 0, 0, 0);
      }
    }
    __syncthreads();
  }

  // epilogue: O^T C-layout: col(q) = c + 16*tn, row(d) = 16*mt + 4*quad + reg
  const int b = bh >> 4, h = bh & 15;
#pragma unroll
  for (int mt = 0; mt < 4; ++mt) {
#pragma unroll
    for (int tnn = 0; tnn < 2; ++tnn) {
      const int tn = (wv << 1) + tnn;
      float4 o;
      o.x = oacc[mt][tnn][0]; o.y = oacc[mt][tnn][1];
      o.z = oacc[mt][tnn][2]; o.w = oacc[mt][tnn][3];
      const size_t off = ((size_t)b * S_LEN + (size_t)(q0 + (tn << 4) + c)) * 1024
                       + (h << 6) + (mt << 4) + (quad << 2);
      *(float4*)(gout + off) = o;
    }
  }
}

extern "C" void kernel_launch(void* const* d_in, const int* in_sizes, int n_in,
                              void* d_out, int out_size, void* d_ws, size_t ws_size,
                              hipStream_t stream) {
  const float* q = (const float*)d_in[0];
  const float* k = (const float*)d_in[1];
  const float* v = (const float*)d_in[2];
  const int* mask = (const int*)d_in[3];
  (void)in_sizes; (void)n_in; (void)out_size; (void)d_ws; (void)ws_size;
  attn_kernel<<<dim3(1024), dim3(256), 0, stream>>>(q, k, v, mask, (float*)d_out);
}